// Round 8
// baseline (87.355 us; speedup 1.0000x reference)
//
#include <hip/hip_runtime.h>

#define SEQ 2048
#define HEADS 16
#define DEPTH 64
#define DIMS 1024
#define LOG2E 1.44269504088896340736f

typedef _Float16 f16x8 __attribute__((ext_vector_type(8)));
typedef _Float16 f16x4 __attribute__((ext_vector_type(4)));
typedef __fp16 fp16v2 __attribute__((ext_vector_type(2)));
typedef float f32x4 __attribute__((ext_vector_type(4)));

__device__ __forceinline__ f32x4 mfma16(f16x8 a, f16x8 b, f32x4 c) {
  return __builtin_amdgcn_mfma_f32_16x16x32_f16(a, b, c, 0, 0, 0);
}

#if __has_builtin(__builtin_amdgcn_exp2f)
#define EXP2(x) __builtin_amdgcn_exp2f(x)
#else
#define EXP2(x) exp2f(x)
#endif

// direct global->LDS DMA, 16B/lane; LDS dest = wave-uniform base + lane*16
#define GLOAD_LDS(g, l)                                                        \
  __builtin_amdgcn_global_load_lds(                                            \
      (const __attribute__((address_space(1))) unsigned int*)(g),              \
      (__attribute__((address_space(3))) unsigned int*)(l), 16, 0, 0)

// ---------- prepass 1: K fp32 [B,S,DIMS] -> fp16 [bh][S][D] ----------
__global__ __launch_bounds__(256) void prep_k(const float* __restrict__ k,
                                              _Float16* __restrict__ kh) {
  int t = blockIdx.x * 256 + threadIdx.x;       // one thread per 8 elems
  size_t flat = (size_t)t * 8;
  int b = (int)(flat >> 21);                    // S*DIMS = 2^21
  int rem = (int)(flat & ((1u << 21) - 1));
  int s = rem >> 10;
  int c = rem & 1023;
  int h = c >> 6;
  int d = c & 63;
  float4 a0 = *(const float4*)(k + flat);
  float4 a1 = *(const float4*)(k + flat + 4);
  float f[8] = {a0.x, a0.y, a0.z, a0.w, a1.x, a1.y, a1.z, a1.w};
  f16x8 th;
  #pragma unroll
  for (int j = 0; j < 8; ++j) th[j] = (_Float16)f[j];
  size_t o = ((size_t)(b * HEADS + h) * SEQ + s) * DEPTH + d;
  *(f16x8*)(kh + o) = th;
}

// ---------- prepass 2: V fp32 [B,S,DIMS] -> Vt fp16 [bh][D][S] ----------
__global__ __launch_bounds__(256) void prep_v(const float* __restrict__ v,
                                              _Float16* __restrict__ vt) {
  int t = blockIdx.x * 256 + threadIdx.x;
  int d = t & 63;                // lanes cover d contiguously -> coalesced reads
  int sg = (t >> 6) & 255;
  int bh = t >> 14;
  int b = bh >> 4, h = bh & 15;
  int s0 = sg * 8;
  const float* src = v + ((size_t)(b * SEQ + s0)) * DIMS + h * DEPTH + d;
  _Float16* dst = vt + ((size_t)bh * DEPTH + d) * SEQ + s0;
  f16x8 tv;
  #pragma unroll
  for (int i = 0; i < 8; ++i) tv[i] = (_Float16)src[(size_t)i * DIMS];
  *(f16x8*)dst = tv;             // 16B contiguous store
}

// ---------- main: flash attention, KV tile 64, 32 q-rows/wave ----------
// V LDS tile linear [64][64] fp16, 16B chunks XOR-swizzled (chunk^=row&7);
// source pre-swizzled for global_load_lds. K read direct global->reg (L2-hot).
__global__ __launch_bounds__(256, 2) void attn_fwd(
    const float* __restrict__ q, const _Float16* __restrict__ kh,
    const _Float16* __restrict__ vt, float* __restrict__ out) {
  __shared__ _Float16 Vl[2][64 * 64];
  __shared__ _Float16 Pl[4][32 * 64];

  const int tid = threadIdx.x;
  const int w = tid >> 6;
  const int l = tid & 63;
  const int lg = l >> 4;
  const int lr = l & 15;

  // XCD-chunked bijective swizzle: 512 blocks = 8 XCDs x 64; consecutive
  // wgs on one XCD share (b,h) -> K/V panel stays in that XCD's L2.
  const int bid = blockIdx.x;
  const int wg = (bid & 7) * 64 + (bid >> 3);
  const int qt = wg & 15;        // q-tile of 128 rows
  const int bh = wg >> 4;        // 0..31
  const int b = bh >> 4;
  const int h = bh & 15;

  const int qb = qt * 128 + w * 32;      // wave's first q row (32 rows/wave)
  const int hoff = h * DEPTH;
  const size_t kvoff = (size_t)bh * SEQ * DEPTH;

  // ---- Q fragments (B-layout: lane holds q-row = mt*16+lr), *log2e ----
  f16x8 qf[2][2];                        // [mt][c]
  #pragma unroll
  for (int mt = 0; mt < 2; ++mt) {
    const float* gq =
        q + (size_t)(b * SEQ + qb + mt * 16 + lr) * DIMS + hoff + 8 * lg;
    #pragma unroll
    for (int c = 0; c < 2; ++c) {
      float4 a0 = *(const float4*)(gq + 32 * c);
      float4 a1 = *(const float4*)(gq + 32 * c + 4);
      float f[8] = {a0.x, a0.y, a0.z, a0.w, a1.x, a1.y, a1.z, a1.w};
      f16x8 t;
      #pragma unroll
      for (int j = 0; j < 8; ++j) t[j] = (_Float16)(f[j] * LOG2E);
      qf[mt][c] = t;
    }
  }

  // ---- per-lane K source (A-frag direct): row lr, col 8*lg (+nt,c strides) --
  const _Float16* gkK = kh + kvoff + (size_t)lr * DEPTH + 8 * lg;
  // ---- V staging source (pre-swizzled column) ----
  const int srow = l >> 3;
  const int scol = ((l & 7) ^ srow) * 8;
  const _Float16* gv0 = vt + kvoff + (size_t)(16 * w + srow) * SEQ + scol;
  _Float16* Pw = &Pl[w][0];

  f32x4 acc[2][4] = {};         // [mt][dt]; C: q = mt*16+4lg+r, d = dt*16+lr
  f32x4 dacc[2] = {};           // denominator in same C layout (rows 4lg+r)
  float mrow[2] = {-3e38f, -3e38f};   // running max (log2 domain), q-row lr

  const int x7 = lr & 7;
  int kch[2];
  #pragma unroll
  for (int c = 0; c < 2; ++c) kch[c] = ((4 * c + lg) ^ x7) * 8;

  const f16x8 onesf = {1, 1, 1, 1, 1, 1, 1, 1};

  // K fragment loads for tile t into an 8-frag register bank (static idx)
  auto kload = [&](int t, f16x8* dst) {
    const _Float16* gk = gkK + (size_t)t * 64 * DEPTH;
    #pragma unroll
    for (int nt = 0; nt < 4; ++nt)
      #pragma unroll
      for (int c = 0; c < 2; ++c)
        dst[nt * 2 + c] =
            *(const f16x8*)(gk + (size_t)(nt * 16) * DEPTH + 32 * c);
  };

  // stage V tile t into buffer buf (2 x global_load_lds per wave)
  auto stageV = [&](int buf, int t) {
    const _Float16* gv = gv0 + (size_t)t * 64;
    GLOAD_LDS(gv, &Vl[buf][(16 * w) * 64]);
    GLOAD_LDS(gv + (size_t)8 * SEQ, &Vl[buf][(16 * w + 8) * 64]);
  };

  auto compute = [&](int buf, f16x8* kf) {
    // ---- QK^T swapped: C[key][q]; lane holds q-col lr, keys nt*16+4lg+r ----
    f32x4 st[2][4] = {};
    __builtin_amdgcn_s_setprio(1);
    #pragma unroll
    for (int nt = 0; nt < 4; ++nt)
      #pragma unroll
      for (int c = 0; c < 2; ++c) {
        st[0][nt] = mfma16(kf[nt * 2 + c], qf[0][c], st[0][nt]);
        st[1][nt] = mfma16(kf[nt * 2 + c], qf[1][c], st[1][nt]);
      }
    __builtin_amdgcn_s_setprio(0);

    // ---- per-set online softmax (log2 domain, defer-max THR=8) + P pack ----
    #pragma unroll
    for (int mt = 0; mt < 2; ++mt) {
      // in-lane max (v_max3 trees); cross-lane reduce only in rescale branch
      float m0 = fmaxf(fmaxf(st[mt][0][0], st[mt][0][1]),
                       fmaxf(st[mt][0][2], st[mt][0][3]));
      float m1 = fmaxf(fmaxf(st[mt][1][0], st[mt][1][1]),
                       fmaxf(st[mt][1][2], st[mt][1][3]));
      float m2 = fmaxf(fmaxf(st[mt][2][0], st[mt][2][1]),
                       fmaxf(st[mt][2][2], st[mt][2][3]));
      float m3 = fmaxf(fmaxf(st[mt][3][0], st[mt][3][1]),
                       fmaxf(st[mt][3][2], st[mt][3][3]));
      float pmax = fmaxf(fmaxf(m0, m1), fmaxf(m2, m3));
      if (!__all(pmax - mrow[mt] <= 8.0f)) {
        pmax = fmaxf(pmax, __shfl_xor(pmax, 16));
        pmax = fmaxf(pmax, __shfl_xor(pmax, 32));
        float mnew = fmaxf(mrow[mt], pmax);
        float sc = EXP2(mrow[mt] - mnew);
        mrow[mt] = mnew;
        #pragma unroll
        for (int r = 0; r < 4; ++r) {
          float scb = __shfl(sc, (l & 48) | (4 * lg + r));
          dacc[mt][r] *= scb;
          #pragma unroll
          for (int dt = 0; dt < 4; ++dt) acc[mt][dt][r] *= scb;
        }
      }
      #pragma unroll
      for (int nt = 0; nt < 4; ++nt) {
        float p0 = EXP2(st[mt][nt][0] - mrow[mt]);
        float p1 = EXP2(st[mt][nt][1] - mrow[mt]);
        float p2 = EXP2(st[mt][nt][2] - mrow[mt]);
        float p3 = EXP2(st[mt][nt][3] - mrow[mt]);
        union { fp16v2 h2[2]; f16x4 h4; } pu;
        pu.h2[0] = __builtin_amdgcn_cvt_pkrtz(p0, p1);
        pu.h2[1] = __builtin_amdgcn_cvt_pkrtz(p2, p3);
        const int chunk = (2 * nt + (lg >> 1)) ^ x7;
        *(f16x4*)&Pw[(mt * 16 + lr) * 64 + chunk * 8 + (lg & 1) * 4] = pu.h4;
      }
    }

    // ---- PV + den: A = P (lane-local q rows), B = V^T / ones ----
    __builtin_amdgcn_s_setprio(1);
    #pragma unroll
    for (int ks = 0; ks < 2; ++ks) {
      f16x8 pf0 = *(const f16x8*)&Pw[(0 * 16 + lr) * 64 + kch[ks]];
      f16x8 pf1 = *(const f16x8*)&Pw[(1 * 16 + lr) * 64 + kch[ks]];
      dacc[0] = mfma16(pf0, onesf, dacc[0]);   // row-sum of P -> denominator
      dacc[1] = mfma16(pf1, onesf, dacc[1]);
      #pragma unroll
      for (int dt = 0; dt < 4; ++dt) {
        f16x8 vf = *(const f16x8*)&Vl[buf][(dt * 16 + lr) * 64 + kch[ks]];
        acc[0][dt] = mfma16(pf0, vf, acc[0][dt]);
        acc[1][dt] = mfma16(pf1, vf, acc[1][dt]);
      }
    }
    __builtin_amdgcn_s_setprio(0);
  };

  // ---- pipeline: K double-banked in regs, V double-buffered in LDS ----
  f16x8 kA[8], kB[8];
  kload(0, kA);
  stageV(0, 0);
  __syncthreads();                      // drains vmcnt -> tile 0 visible
  for (int kt = 0; kt < SEQ / 64; kt += 2) {
    stageV(1, kt + 1);                  // V odd tile in flight
    kload(kt + 1, kB);                  // K odd tile -> regs (overlaps compute)
    compute(0, kA);
    __syncthreads();                    // drain + WAR fence
    if (kt + 2 < SEQ / 64) {
      stageV(0, kt + 2);
      kload(kt + 2, kA);
    }
    compute(1, kB);
    __syncthreads();
  }

  // ---- epilogue: den already in acc layout -> no shfl; coalesced stores ----
  #pragma unroll
  for (int mt = 0; mt < 2; ++mt) {
    f32x4 rden;
    #pragma unroll
    for (int r = 0; r < 4; ++r) rden[r] = 1.0f / dacc[mt][r];
    #pragma unroll
    for (int dt = 0; dt < 4; ++dt)
      #pragma unroll
      for (int r = 0; r < 4; ++r) {
        const int row = qb + mt * 16 + 4 * lg + r;
        out[(size_t)(b * SEQ + row) * DIMS + hoff + dt * 16 + lr] =
            acc[mt][dt][r] * rden[r];
      }
  }
}

extern "C" void kernel_launch(void* const* d_in, const int* in_sizes, int n_in,
                              void* d_out, int out_size, void* d_ws, size_t ws_size,
                              hipStream_t stream) {
  const float* q = (const float*)d_in[0];
  const float* k = (const float*)d_in[1];
  const float* v = (const float*)d_in[2];
  float* out = (float*)d_out;

  // workspace: Khf | Vt, each 2*16*2048*64 fp16 = 8 MiB
  const size_t tsz = (size_t)2 * HEADS * SEQ * DEPTH;  // elements
  _Float16* khf = (_Float16*)d_ws;
  _Float16* vtp = khf + tsz;

  prep_k<<<2048, 256, 0, stream>>>(k, khf);
  prep_v<<<2048, 256, 0, stream>>>(v, vtp);
  attn_fwd<<<512, 256, 0, stream>>>(q, khf, vtp, out);
}

// Round 9
// 75.215 us; speedup vs baseline: 1.1614x; 1.1614x over previous
//
#include <hip/hip_runtime.h>

#define SEQ 2048
#define HEADS 16
#define DEPTH 64
#define DIMS 1024
#define LOG2E 1.44269504088896340736f

typedef _Float16 f16x8 __attribute__((ext_vector_type(8)));
typedef _Float16 f16x4 __attribute__((ext_vector_type(4)));
typedef __fp16 fp16v2 __attribute__((ext_vector_type(2)));
typedef float f32x4 __attribute__((ext_vector_type(4)));

__device__ __forceinline__ f32x4 mfma16(f16x8 a, f16x8 b, f32x4 c) {
  return __builtin_amdgcn_mfma_f32_16x16x32_f16(a, b, c, 0, 0, 0);
}

#if __has_builtin(__builtin_amdgcn_exp2f)
#define EXP2(x) __builtin_amdgcn_exp2f(x)
#else
#define EXP2(x) exp2f(x)
#endif

// direct global->LDS DMA, 16B/lane; LDS dest = wave-uniform base + lane*16
#define GLOAD_LDS(g, l)                                                        \
  __builtin_amdgcn_global_load_lds(                                            \
      (const __attribute__((address_space(1))) unsigned int*)(g),              \
      (__attribute__((address_space(3))) unsigned int*)(l), 16, 0, 0)

// ---------- prepass 1: K fp32 [B,S,DIMS] -> fp16 [bh][S][D] ----------
__global__ __launch_bounds__(256) void prep_k(const float* __restrict__ k,
                                              _Float16* __restrict__ kh) {
  int t = blockIdx.x * 256 + threadIdx.x;       // one thread per 8 elems
  size_t flat = (size_t)t * 8;
  int b = (int)(flat >> 21);                    // S*DIMS = 2^21
  int rem = (int)(flat & ((1u << 21) - 1));
  int s = rem >> 10;
  int c = rem & 1023;
  int h = c >> 6;
  int d = c & 63;
  float4 a0 = *(const float4*)(k + flat);
  float4 a1 = *(const float4*)(k + flat + 4);
  float f[8] = {a0.x, a0.y, a0.z, a0.w, a1.x, a1.y, a1.z, a1.w};
  f16x8 th;
  #pragma unroll
  for (int j = 0; j < 8; ++j) th[j] = (_Float16)f[j];
  size_t o = ((size_t)(b * HEADS + h) * SEQ + s) * DEPTH + d;
  *(f16x8*)(kh + o) = th;
}

// ---------- prepass 2: V fp32 [B,S,DIMS] -> Vt fp16 [bh][D][S] ----------
__global__ __launch_bounds__(256) void prep_v(const float* __restrict__ v,
                                              _Float16* __restrict__ vt) {
  int t = blockIdx.x * 256 + threadIdx.x;
  int d = t & 63;                // lanes cover d contiguously -> coalesced reads
  int sg = (t >> 6) & 255;
  int bh = t >> 14;
  int b = bh >> 4, h = bh & 15;
  int s0 = sg * 8;
  const float* src = v + ((size_t)(b * SEQ + s0)) * DIMS + h * DEPTH + d;
  _Float16* dst = vt + ((size_t)bh * DEPTH + d) * SEQ + s0;
  f16x8 tv;
  #pragma unroll
  for (int i = 0; i < 8; ++i) tv[i] = (_Float16)src[(size_t)i * DIMS];
  *(f16x8*)dst = tv;             // 16B contiguous store
}

// ---------- main: flash attention, KV tile 64, 32 q-rows/wave ----------
// LDS tiles linear [64][64] fp16, 16B chunks XOR-swizzled (chunk^=row&7);
// K/V source pre-swizzled for global_load_lds; P swizzled write+read.
// Pipeline: QK^T(t+1) issued BEFORE softmax(t) so its MFMAs overlap the
// softmax VALU (disjoint registers). K 2-buf, V 3-buf, 1 barrier/tile.
__global__ __launch_bounds__(256, 2) void attn_fwd(
    const float* __restrict__ q, const _Float16* __restrict__ kh,
    const _Float16* __restrict__ vt, float* __restrict__ out) {
  __shared__ _Float16 Kl[2][64 * 64];
  __shared__ _Float16 Vl[3][64 * 64];
  __shared__ _Float16 Pl[4][32 * 64];

  const int tid = threadIdx.x;
  const int w = tid >> 6;
  const int l = tid & 63;
  const int lg = l >> 4;
  const int lr = l & 15;

  // XCD-chunked bijective swizzle: 512 blocks = 8 XCDs x 64; consecutive
  // wgs on one XCD share (b,h) -> K/V panel stays in that XCD's L2.
  const int bid = blockIdx.x;
  const int wg = (bid & 7) * 64 + (bid >> 3);
  const int qt = wg & 15;        // q-tile of 128 rows
  const int bh = wg >> 4;        // 0..31
  const int b = bh >> 4;
  const int h = bh & 15;

  const int qb = qt * 128 + w * 32;      // wave's first q row (32 rows/wave)
  const int hoff = h * DEPTH;
  const size_t kvoff = (size_t)bh * SEQ * DEPTH;

  // ---- Q fragments (B-layout: lane holds q-row = mt*16+lr), *log2e ----
  f16x8 qf[2][2];                        // [mt][c]
  #pragma unroll
  for (int mt = 0; mt < 2; ++mt) {
    const float* gq =
        q + (size_t)(b * SEQ + qb + mt * 16 + lr) * DIMS + hoff + 8 * lg;
    #pragma unroll
    for (int c = 0; c < 2; ++c) {
      float4 a0 = *(const float4*)(gq + 32 * c);
      float4 a1 = *(const float4*)(gq + 32 * c + 4);
      float f[8] = {a0.x, a0.y, a0.z, a0.w, a1.x, a1.y, a1.z, a1.w};
      f16x8 t;
      #pragma unroll
      for (int j = 0; j < 8; ++j) t[j] = (_Float16)(f[j] * LOG2E);
      qf[mt][c] = t;
    }
  }

  // ---- per-lane staging source (source column pre-swizzled) ----
  const int srow = l >> 3;                       // row-in-8 for this lane
  const int scol = ((l & 7) ^ srow) * 8;         // inverse-swizzled column
  const _Float16* gk0 = kh + kvoff + (size_t)(16 * w + srow) * DEPTH + scol;
  const _Float16* gv0 = vt + kvoff + (size_t)(16 * w + srow) * SEQ + scol;
  _Float16* Pw = &Pl[w][0];

  f32x4 acc[2][4] = {};         // [mt][dt]; C: q = mt*16+4lg+r, d = dt*16+lr
  f32x4 dacc[2] = {};           // denominator in same C layout (rows 4lg+r)
  float mrow[2] = {-3e38f, -3e38f};   // running max (log2 domain), q-row lr

  const int x7 = lr & 7;
  int kch[2];
  #pragma unroll
  for (int c = 0; c < 2; ++c) kch[c] = ((4 * c + lg) ^ x7) * 8;

  const f16x8 onesf = {1, 1, 1, 1, 1, 1, 1, 1};

  // stage tile t: K -> Kl[kb], V -> Vl[vb] (4 x global_load_lds per wave)
  auto stageKV = [&](int t, int kb, int vb) {
    const _Float16* gk = gk0 + (size_t)t * 64 * DEPTH;
    const _Float16* gv = gv0 + (size_t)t * 64;
    GLOAD_LDS(gk, &Kl[kb][(16 * w) * 64]);
    GLOAD_LDS(gk + 8 * DEPTH, &Kl[kb][(16 * w + 8) * 64]);
    GLOAD_LDS(gv, &Vl[vb][(16 * w) * 64]);
    GLOAD_LDS(gv + (size_t)8 * SEQ, &Vl[vb][(16 * w + 8) * 64]);
  };

  // QK^T swapped: C[key][q]; lane holds q-col lr, keys nt*16+4lg+r
  auto qkt = [&](int kb, f32x4 (&st)[2][4]) {
    #pragma unroll
    for (int mt = 0; mt < 2; ++mt)
      #pragma unroll
      for (int nt = 0; nt < 4; ++nt) st[mt][nt] = f32x4{0.f, 0.f, 0.f, 0.f};
    __builtin_amdgcn_s_setprio(1);
    #pragma unroll
    for (int nt = 0; nt < 4; ++nt)
      #pragma unroll
      for (int c = 0; c < 2; ++c) {
        f16x8 kf = *(const f16x8*)&Kl[kb][(nt * 16 + lr) * 64 + kch[c]];
        st[0][nt] = mfma16(kf, qf[0][c], st[0][nt]);
        st[1][nt] = mfma16(kf, qf[1][c], st[1][nt]);
      }
    __builtin_amdgcn_s_setprio(0);
  };

  // softmax (log2 domain, defer-max THR=8) + P pack + PV from Vl[vb]
  auto smax_pv = [&](f32x4 (&st)[2][4], int vb) {
    #pragma unroll
    for (int mt = 0; mt < 2; ++mt) {
      float m0 = fmaxf(fmaxf(st[mt][0][0], st[mt][0][1]),
                       fmaxf(st[mt][0][2], st[mt][0][3]));
      float m1 = fmaxf(fmaxf(st[mt][1][0], st[mt][1][1]),
                       fmaxf(st[mt][1][2], st[mt][1][3]));
      float m2 = fmaxf(fmaxf(st[mt][2][0], st[mt][2][1]),
                       fmaxf(st[mt][2][2], st[mt][2][3]));
      float m3 = fmaxf(fmaxf(st[mt][3][0], st[mt][3][1]),
                       fmaxf(st[mt][3][2], st[mt][3][3]));
      float pmax = fmaxf(fmaxf(m0, m1), fmaxf(m2, m3));
      if (!__all(pmax - mrow[mt] <= 8.0f)) {
        pmax = fmaxf(pmax, __shfl_xor(pmax, 16));
        pmax = fmaxf(pmax, __shfl_xor(pmax, 32));
        float mnew = fmaxf(mrow[mt], pmax);
        float sc = EXP2(mrow[mt] - mnew);
        mrow[mt] = mnew;
        #pragma unroll
        for (int r = 0; r < 4; ++r) {
          float scb = __shfl(sc, (l & 48) | (4 * lg + r));
          dacc[mt][r] *= scb;
          #pragma unroll
          for (int dt = 0; dt < 4; ++dt) acc[mt][dt][r] *= scb;
        }
      }
      #pragma unroll
      for (int nt = 0; nt < 4; ++nt) {
        float p0 = EXP2(st[mt][nt][0] - mrow[mt]);
        float p1 = EXP2(st[mt][nt][1] - mrow[mt]);
        float p2 = EXP2(st[mt][nt][2] - mrow[mt]);
        float p3 = EXP2(st[mt][nt][3] - mrow[mt]);
        union { fp16v2 h2[2]; f16x4 h4; } pu;
        pu.h2[0] = __builtin_amdgcn_cvt_pkrtz(p0, p1);
        pu.h2[1] = __builtin_amdgcn_cvt_pkrtz(p2, p3);
        const int chunk = (2 * nt + (lg >> 1)) ^ x7;
        *(f16x4*)&Pw[(mt * 16 + lr) * 64 + chunk * 8 + (lg & 1) * 4] = pu.h4;
      }
    }
    // PV + den: A = P (lane-local q rows), B = V^T / ones
    __builtin_amdgcn_s_setprio(1);
    #pragma unroll
    for (int ks = 0; ks < 2; ++ks) {
      f16x8 pf0 = *(const f16x8*)&Pw[(0 * 16 + lr) * 64 + kch[ks]];
      f16x8 pf1 = *(const f16x8*)&Pw[(1 * 16 + lr) * 64 + kch[ks]];
      dacc[0] = mfma16(pf0, onesf, dacc[0]);   // row-sum of P -> denominator
      dacc[1] = mfma16(pf1, onesf, dacc[1]);
      #pragma unroll
      for (int dt = 0; dt < 4; ++dt) {
        f16x8 vf = *(const f16x8*)&Vl[vb][(dt * 16 + lr) * 64 + kch[ks]];
        acc[0][dt] = mfma16(pf0, vf, acc[0][dt]);
        acc[1][dt] = mfma16(pf1, vf, acc[1][dt]);
      }
    }
    __builtin_amdgcn_s_setprio(0);
  };

  // ---- pipeline: QK^T one tile ahead of softmax/PV; 1 barrier per tile ----
  f32x4 stA[2][4], stB[2][4];
  stageKV(0, 0, 0);
  __syncthreads();               // tile 0 visible
  stageKV(1, 1, 1);
  qkt(0, stA);                   // scores(0); MFMAs run behind the barrier
  __syncthreads();               // tile 1 visible
  // loop bodies hardcode buffer indices (t is always even):
  //   body A (tile t):   V = va,           next-scores K = 1, stage t+2 -> K0,V v2
  //   body B (tile t+1): V = v1,           next-scores K = 0, stage t+3 -> K1,V va
  int va = 0;
  #pragma unroll 1
  for (int t = 0; t < SEQ / 64; t += 2) {
    const int v1 = va == 2 ? 0 : va + 1;
    const int v2 = v1 == 2 ? 0 : v1 + 1;
    if (t + 2 < SEQ / 64) stageKV(t + 2, 0, v2);
    qkt(1, stB);                 // scores(t+1) — overlaps softmax(t) VALU
    smax_pv(stA, va);
    __syncthreads();
    if (t + 3 < SEQ / 64) stageKV(t + 3, 1, va);
    if (t + 2 < SEQ / 64) qkt(0, stA);  // scores(t+2) — overlaps softmax(t+1)
    smax_pv(stB, v1);
    __syncthreads();
    va = v2;
  }

  // ---- epilogue: den already in acc layout -> no shfl; coalesced stores ----
  #pragma unroll
  for (int mt = 0; mt < 2; ++mt) {
    f32x4 rden;
    #pragma unroll
    for (int r = 0; r < 4; ++r) rden[r] = 1.0f / dacc[mt][r];
    #pragma unroll
    for (int dt = 0; dt < 4; ++dt)
      #pragma unroll
      for (int r = 0; r < 4; ++r) {
        const int row = qb + mt * 16 + 4 * lg + r;
        out[(size_t)(b * SEQ + row) * DIMS + hoff + dt * 16 + lr] =
            acc[mt][dt][r] * rden[r];
      }
  }
}

extern "C" void kernel_launch(void* const* d_in, const int* in_sizes, int n_in,
                              void* d_out, int out_size, void* d_ws, size_t ws_size,
                              hipStream_t stream) {
  const float* q = (const float*)d_in[0];
  const float* k = (const float*)d_in[1];
  const float* v = (const float*)d_in[2];
  float* out = (float*)d_out;

  // workspace: Khf | Vt, each 2*16*2048*64 fp16 = 8 MiB
  const size_t tsz = (size_t)2 * HEADS * SEQ * DEPTH;  // elements
  _Float16* khf = (_Float16*)d_ws;
  _Float16* vtp = khf + tsz;

  prep_k<<<2048, 256, 0, stream>>>(k, khf);
  prep_v<<<2048, 256, 0, stream>>>(v, vtp);
  attn_fwd<<<512, 256, 0, stream>>>(q, khf, vtp, out);
}

// Round 10
// 72.566 us; speedup vs baseline: 1.2038x; 1.0365x over previous
//
#include <hip/hip_runtime.h>

#define SEQ 2048
#define HEADS 16
#define DEPTH 64
#define DIMS 1024
#define LOG2E 1.44269504088896340736f

typedef _Float16 f16x8 __attribute__((ext_vector_type(8)));
typedef __fp16 fp16v2 __attribute__((ext_vector_type(2)));
typedef float f32x16 __attribute__((ext_vector_type(16)));

__device__ __forceinline__ f32x16 mfma32(f16x8 a, f16x8 b, f32x16 c) {
  return __builtin_amdgcn_mfma_f32_32x32x16_f16(a, b, c, 0, 0, 0);
}

#if __has_builtin(__builtin_amdgcn_exp2f)
#define EXP2(x) __builtin_amdgcn_exp2f(x)
#else
#define EXP2(x) exp2f(x)
#endif

__device__ __forceinline__ unsigned pkbits(float a, float b) {
  union { fp16v2 h; unsigned u; } cv;
  cv.h = __builtin_amdgcn_cvt_pkrtz(a, b);
  return cv.u;
}

// direct global->LDS DMA, 16B/lane; LDS dest = wave-uniform base + lane*16
#define GLOAD_LDS(g, l)                                                        \
  __builtin_amdgcn_global_load_lds(                                            \
      (const __attribute__((address_space(1))) unsigned int*)(g),              \
      (__attribute__((address_space(3))) unsigned int*)(l), 16, 0, 0)

// ---------- fused prepass: K -> fp16 [bh][S][D];  V -> fp16 [bh][D][S] ------
__global__ __launch_bounds__(256) void prep_kv(const float* __restrict__ k,
                                               const float* __restrict__ v,
                                               _Float16* __restrict__ khf,
                                               _Float16* __restrict__ vtp) {
  const int bid = blockIdx.x;
  if (bid < 2048) {              // ---- K half: one thread per 8 elems ----
    int t = bid * 256 + threadIdx.x;
    size_t flat = (size_t)t * 8;
    int b = (int)(flat >> 21);                    // S*DIMS = 2^21
    int rem = (int)(flat & ((1u << 21) - 1));
    int s = rem >> 10;
    int c = rem & 1023;
    int h = c >> 6;
    int d = c & 63;
    float4 a0 = *(const float4*)(k + flat);
    float4 a1 = *(const float4*)(k + flat + 4);
    float f[8] = {a0.x, a0.y, a0.z, a0.w, a1.x, a1.y, a1.z, a1.w};
    f16x8 th;
    #pragma unroll
    for (int j = 0; j < 8; ++j) th[j] = (_Float16)f[j];
    size_t o = ((size_t)(b * HEADS + h) * SEQ + s) * DEPTH + d;
    *(f16x8*)(khf + o) = th;
  } else {                       // ---- V half: transpose to [bh][D][S] ----
    int t = (bid - 2048) * 256 + threadIdx.x;
    int d = t & 63;
    int sg = (t >> 6) & 255;
    int bh = t >> 14;
    int b = bh >> 4, h = bh & 15;
    int s0 = sg * 8;
    const float* src = v + ((size_t)(b * SEQ + s0)) * DIMS + h * DEPTH + d;
    _Float16* dst = vtp + ((size_t)bh * DEPTH + d) * SEQ + s0;
    f16x8 tv;
    #pragma unroll
    for (int i = 0; i < 8; ++i) tv[i] = (_Float16)src[(size_t)i * DIMS];
    *(f16x8*)dst = tv;
  }
}

// ---------- main: flash attention, 32x32x16 MFMA, 32 q-rows/wave ----------
// LDS tiles linear [64][64] fp16, 16B chunks XOR-swizzled (chunk^=row&7);
// source pre-swizzled for global_load_lds. P never touches LDS: swapped
// QK^T C-layout -> PV A-fragments via cvt_pk + v_permlane32_swap_b32 (T12).
__global__ __launch_bounds__(256, 2) void attn_fwd(
    const float* __restrict__ q, const _Float16* __restrict__ kh,
    const _Float16* __restrict__ vt, float* __restrict__ out) {
  __shared__ _Float16 Kl[2][64 * 64];
  __shared__ _Float16 Vl[2][64 * 64];

  const int tid = threadIdx.x;
  const int w = tid >> 6;
  const int l = tid & 63;
  const int q32 = l & 31;        // lane's q-row (and V d-row) index
  const int hi = l >> 5;

  // XCD-chunked bijective swizzle: 512 blocks = 8 XCDs x 64.
  const int bid = blockIdx.x;
  const int wg = (bid & 7) * 64 + (bid >> 3);
  const int qt = wg & 15;        // q-tile of 128 rows
  const int bh = wg >> 4;        // 0..31
  const int b = bh >> 4;
  const int h = bh & 15;

  const int qb = qt * 128 + w * 32;      // wave's first q row (32 rows/wave)
  const int hoff = h * DEPTH;
  const size_t kvoff = (size_t)bh * SEQ * DEPTH;

  // ---- Q B-fragments (n = q = q32, k-step c: dims c*16 + 8*hi + j), *log2e
  f16x8 qf[4];
  {
    const float* gq = q + (size_t)(b * SEQ + qb + q32) * DIMS + hoff + 8 * hi;
    #pragma unroll
    for (int c = 0; c < 4; ++c) {
      float4 a0 = *(const float4*)(gq + 16 * c);
      float4 a1 = *(const float4*)(gq + 16 * c + 4);
      float f[8] = {a0.x, a0.y, a0.z, a0.w, a1.x, a1.y, a1.z, a1.w};
      f16x8 t;
      #pragma unroll
      for (int j = 0; j < 8; ++j) t[j] = (_Float16)(f[j] * LOG2E);
      qf[c] = t;
    }
  }

  // ---- staging source (column pre-swizzled for linear LDS dest) ----
  const int srow = l >> 3;
  const int scol = ((l & 7) ^ srow) * 8;
  const _Float16* gk0 = kh + kvoff + (size_t)(16 * w + srow) * DEPTH + scol;
  const _Float16* gv0 = vt + kvoff + (size_t)(16 * w + srow) * SEQ + scol;

  // swizzled fragment-read offsets: chunk (2*i + hi) of row (row&7 == q32&7)
  const int x7 = q32 & 7;
  int off[4];
  #pragma unroll
  for (int i = 0; i < 4; ++i) off[i] = ((2 * i + hi) ^ x7) * 8;

  f32x16 acc0 = {}, acc1 = {};   // O: col d = q32 (+32), row q = crow(r,hi)
  float mrow = -3e38f;           // running max (log2 domain) for q-row q32
  float den = 0.f;               // running denominator (replicated over hi)

  auto stage = [&](int buf, int t) {
    const _Float16* gk = gk0 + (size_t)t * 64 * DEPTH;
    const _Float16* gv = gv0 + (size_t)t * 64;
    GLOAD_LDS(gk, &Kl[buf][(16 * w) * 64]);
    GLOAD_LDS(gk + 8 * DEPTH, &Kl[buf][(16 * w + 8) * 64]);
    GLOAD_LDS(gv, &Vl[buf][(16 * w) * 64]);
    GLOAD_LDS(gv + (size_t)8 * SEQ, &Vl[buf][(16 * w + 8) * 64]);
  };

  auto compute = [&](int buf) {
    // ---- QK^T swapped: st = mfma(K, Q): C[key][q], q = q32 lane-local ----
    f32x16 st0 = {}, st1 = {};
    __builtin_amdgcn_s_setprio(1);
    #pragma unroll
    for (int c = 0; c < 4; ++c) {
      f16x8 kf0 = *(const f16x8*)&Kl[buf][q32 * 64 + off[c]];
      f16x8 kf1 = *(const f16x8*)&Kl[buf][(32 + q32) * 64 + off[c]];
      st0 = mfma32(kf0, qf[c], st0);
      st1 = mfma32(kf1, qf[c], st1);
    }
    __builtin_amdgcn_s_setprio(0);

    // ---- online softmax: all 32 scores of q-row q32 are in-lane ----
    float mx = fmaxf(st0[0], st1[0]);
    #pragma unroll
    for (int r = 1; r < 16; ++r) mx = fmaxf(mx, fmaxf(st0[r], st1[r]));
    if (!__all(mx - mrow <= 8.0f)) {       // defer-max THR=8
      mx = fmaxf(mx, __shfl_xor(mx, 32));
      float mnew = fmaxf(mrow, mx);
      float sc = EXP2(mrow - mnew);
      mrow = mnew;
      den *= sc;
      #pragma unroll
      for (int r = 0; r < 16; ++r) {
        const int crow = (r & 3) + 8 * (r >> 2) + 4 * hi;
        float scb = __shfl(sc, crow);
        acc0[r] *= scb;
        acc1[r] *= scb;
      }
    }
    float p0[16], p1[16];
    float rs = 0.f;
    #pragma unroll
    for (int r = 0; r < 16; ++r) {
      p0[r] = EXP2(st0[r] - mrow);
      p1[r] = EXP2(st1[r] - mrow);
      rs += p0[r] + p1[r];
    }
    rs += __shfl_xor(rs, 32);
    den += rs;

    // ---- P -> PV A-fragments in-register (cvt_pk + permlane32_swap) ----
    // key = (r&3) + 8*(r>>2) + 4*hi; step s needs keys 16s+8hi..+7.
    // swap(X=pk(p[8s],p[8s+1]), Y=pk(p[8s+4],p[8s+5])) -> X'=j0-1, Y'=j4-5.
    f16x8 pa[4];
    auto mkpa = [&](const float* pp, f16x8* dst) {
      #pragma unroll
      for (int sl = 0; sl < 2; ++sl) {
        unsigned x0 = pkbits(pp[8 * sl + 0], pp[8 * sl + 1]);
        unsigned x1 = pkbits(pp[8 * sl + 2], pp[8 * sl + 3]);
        unsigned y0 = pkbits(pp[8 * sl + 4], pp[8 * sl + 5]);
        unsigned y1 = pkbits(pp[8 * sl + 6], pp[8 * sl + 7]);
        asm("v_permlane32_swap_b32 %0, %1" : "+v"(x0), "+v"(y0));
        asm("v_permlane32_swap_b32 %0, %1" : "+v"(x1), "+v"(y1));
        union { unsigned u[4]; f16x8 v; } pu;
        pu.u[0] = x0; pu.u[1] = x1; pu.u[2] = y0; pu.u[3] = y1;
        dst[sl] = pu.v;
      }
    };
    mkpa(p0, &pa[0]);
    mkpa(p1, &pa[2]);

    // ---- PV: acc[dt] += pa[s] x V^T[dt][keys 16s..]; A=P lane-local ----
    __builtin_amdgcn_s_setprio(1);
    #pragma unroll
    for (int s = 0; s < 4; ++s) {
      f16x8 vf0 = *(const f16x8*)&Vl[buf][q32 * 64 + off[s]];
      f16x8 vf1 = *(const f16x8*)&Vl[buf][(32 + q32) * 64 + off[s]];
      acc0 = mfma32(pa[s], vf0, acc0);
      acc1 = mfma32(pa[s], vf1, acc1);
    }
    __builtin_amdgcn_s_setprio(0);
  };

  // ---- 2-phase pipeline: stage t+1 early, ONE barrier per tile ----
  stage(0, 0);
  __syncthreads();                      // drains vmcnt -> tile 0 visible
  #pragma unroll 1
  for (int kt = 0; kt < SEQ / 64; kt += 2) {
    stage(1, kt + 1);                   // in flight during compute
    compute(0);
    __syncthreads();                    // drain + WAR fence
    if (kt + 2 < SEQ / 64) stage(0, kt + 2);
    compute(1);
    __syncthreads();
  }

  // ---- epilogue: den broadcast per C-row, normalize, coalesced stores ----
  #pragma unroll
  for (int r = 0; r < 16; ++r) {
    const int crow = (r & 3) + 8 * (r >> 2) + 4 * hi;
    float dn = __shfl(den, crow);       // den replicated across hi halves
    float rden = 1.0f / dn;
    float* po = out + (size_t)(b * SEQ + qb + crow) * DIMS + hoff;
    po[q32] = acc0[r] * rden;
    po[32 + q32] = acc1[r] * rden;
  }
}

extern "C" void kernel_launch(void* const* d_in, const int* in_sizes, int n_in,
                              void* d_out, int out_size, void* d_ws, size_t ws_size,
                              hipStream_t stream) {
  const float* q = (const float*)d_in[0];
  const float* k = (const float*)d_in[1];
  const float* v = (const float*)d_in[2];
  float* out = (float*)d_out;

  // workspace: Khf | Vt, each 2*16*2048*64 fp16 = 8 MiB
  const size_t tsz = (size_t)2 * HEADS * SEQ * DEPTH;  // elements
  _Float16* khf = (_Float16*)d_ws;
  _Float16* vtp = khf + tsz;

  prep_kv<<<4096, 256, 0, stream>>>(k, v, khf, vtp);
  attn_fwd<<<512, 256, 0, stream>>>(q, khf, vtp, out);
}

// Round 11
// 70.577 us; speedup vs baseline: 1.2377x; 1.0282x over previous
//
#include <hip/hip_runtime.h>

#define SEQ 2048
#define HEADS 16
#define DEPTH 64
#define DIMS 1024
#define LOG2E 1.44269504088896340736f

typedef _Float16 f16x8 __attribute__((ext_vector_type(8)));
typedef __fp16 fp16v2 __attribute__((ext_vector_type(2)));
typedef float f32x16 __attribute__((ext_vector_type(16)));

__device__ __forceinline__ f32x16 mfma32(f16x8 a, f16x8 b, f32x16 c) {
  return __builtin_amdgcn_mfma_f32_32x32x16_f16(a, b, c, 0, 0, 0);
}

#if __has_builtin(__builtin_amdgcn_exp2f)
#define EXP2(x) __builtin_amdgcn_exp2f(x)
#else
#define EXP2(x) exp2f(x)
#endif

__device__ __forceinline__ unsigned pkbits(float a, float b) {
  union { fp16v2 h; unsigned u; } cv;
  cv.h = __builtin_amdgcn_cvt_pkrtz(a, b);
  return cv.u;
}

// direct global->LDS DMA, 16B/lane; LDS dest = wave-uniform base + lane*16
#define GLOAD_LDS(g, l)                                                        \
  __builtin_amdgcn_global_load_lds(                                            \
      (const __attribute__((address_space(1))) unsigned int*)(g),              \
      (__attribute__((address_space(3))) unsigned int*)(l), 16, 0, 0)

// ---------- fused prepass: K -> fp16 [bh][S][D];  V -> fp16 [bh][D][S] ------
__global__ __launch_bounds__(256) void prep_kv(const float* __restrict__ k,
                                               const float* __restrict__ v,
                                               _Float16* __restrict__ khf,
                                               _Float16* __restrict__ vtp) {
  const int bid = blockIdx.x;
  if (bid < 2048) {              // ---- K half: one thread per 8 elems ----
    int t = bid * 256 + threadIdx.x;
    size_t flat = (size_t)t * 8;
    int b = (int)(flat >> 21);                    // S*DIMS = 2^21
    int rem = (int)(flat & ((1u << 21) - 1));
    int s = rem >> 10;
    int c = rem & 1023;
    int h = c >> 6;
    int d = c & 63;
    float4 a0 = *(const float4*)(k + flat);
    float4 a1 = *(const float4*)(k + flat + 4);
    float f[8] = {a0.x, a0.y, a0.z, a0.w, a1.x, a1.y, a1.z, a1.w};
    f16x8 th;
    #pragma unroll
    for (int j = 0; j < 8; ++j) th[j] = (_Float16)f[j];
    size_t o = ((size_t)(b * HEADS + h) * SEQ + s) * DEPTH + d;
    *(f16x8*)(khf + o) = th;
  } else {                       // ---- V half: transpose to [bh][D][S] ----
    int t = (bid - 2048) * 256 + threadIdx.x;
    int d = t & 63;
    int sg = (t >> 6) & 255;
    int bh = t >> 14;
    int b = bh >> 4, h = bh & 15;
    int s0 = sg * 8;
    const float* src = v + ((size_t)(b * SEQ + s0)) * DIMS + h * DEPTH + d;
    _Float16* dst = vtp + ((size_t)bh * DEPTH + d) * SEQ + s0;
    f16x8 tv;
    #pragma unroll
    for (int i = 0; i < 8; ++i) tv[i] = (_Float16)src[(size_t)i * DIMS];
    *(f16x8*)dst = tv;
  }
}

// ---------- main: flash attention, 32x32x16 MFMA, 32 q-rows/wave ----------
// LDS tiles linear [64][64] fp16. 16B chunk c of row r lives at LDS chunk
// c ^ mask(r), mask(r) = (r&7) ^ ((r>>3)&3)  -> fragment reads hit each
// 16B chunk-column with exactly 8 lanes (conflict-free). Sources are
// pre-swizzled per-lane for global_load_lds. P never touches LDS (T12:
// cvt_pk + v_permlane32_swap). den via ones-MFMA in C-layout.
// Pipeline: QK^T(t+1) issued before softmax(t); K 2-buf, V 3-buf.
__global__ __launch_bounds__(256, 2) void attn_fwd(
    const float* __restrict__ q, const _Float16* __restrict__ kh,
    const _Float16* __restrict__ vt, float* __restrict__ out) {
  __shared__ _Float16 Kl[2][64 * 64];
  __shared__ _Float16 Vl[3][64 * 64];

  const int tid = threadIdx.x;
  const int w = tid >> 6;
  const int l = tid & 63;
  const int q32 = l & 31;        // lane's q-row (and V d-row) index
  const int hi = l >> 5;

  // XCD-chunked bijective swizzle: 512 blocks = 8 XCDs x 64.
  const int bid = blockIdx.x;
  const int wg = (bid & 7) * 64 + (bid >> 3);
  const int qt = wg & 15;        // q-tile of 128 rows
  const int bh = wg >> 4;        // 0..31
  const int b = bh >> 4;
  const int h = bh & 15;

  const int qb = qt * 128 + w * 32;      // wave's first q row (32 rows/wave)
  const int hoff = h * DEPTH;
  const size_t kvoff = (size_t)bh * SEQ * DEPTH;

  // ---- Q B-fragments (n = q = q32, k-step c: dims c*16 + 8*hi + j), *log2e
  f16x8 qf[4];
  {
    const float* gq = q + (size_t)(b * SEQ + qb + q32) * DIMS + hoff + 8 * hi;
    #pragma unroll
    for (int c = 0; c < 4; ++c) {
      float4 a0 = *(const float4*)(gq + 16 * c);
      float4 a1 = *(const float4*)(gq + 16 * c + 4);
      float f[8] = {a0.x, a0.y, a0.z, a0.w, a1.x, a1.y, a1.z, a1.w};
      f16x8 t;
      #pragma unroll
      for (int j = 0; j < 8; ++j) t[j] = (_Float16)(f[j] * LOG2E);
      qf[c] = t;
    }
  }

  // ---- staging sources (per-lane pre-swizzle, octave-aware mask) ----
  // gload i of wave w writes LDS rows 16w+8i .. +7; lane l -> row +(l>>3),
  // chunk l&7. Data chunk there = (l&7) ^ (l>>3) ^ ((2w+i)&3).
  const int j8 = l >> 3;
  const int sch0 = (l & 7) ^ j8 ^ ((2 * w) & 3);
  const int sch1 = sch0 ^ 1;     // ((2w+1)&3) = ((2w)&3)^1
  const _Float16* gkA = kh + kvoff + (size_t)(16 * w + j8) * DEPTH + sch0 * 8;
  const _Float16* gkB =
      kh + kvoff + (size_t)(16 * w + 8 + j8) * DEPTH + sch1 * 8;
  const _Float16* gvA = vt + kvoff + (size_t)(16 * w + j8) * SEQ + sch0 * 8;
  const _Float16* gvB =
      vt + kvoff + (size_t)(16 * w + 8 + j8) * SEQ + sch1 * 8;

  // fragment-read offsets: chunk (2c+hi) of rows q32 / 32+q32 (same mask)
  const int mask0 = (q32 & 7) ^ ((q32 >> 3) & 3);
  int off[4];
  #pragma unroll
  for (int c = 0; c < 4; ++c) off[c] = ((2 * c + hi) ^ mask0) * 8;

  f32x16 acc0 = {}, acc1 = {};   // O: col d = q32 (+32), row q = crow(r,hi)
  f32x16 dacc = {};              // denominator, same C rows (cols replicated)
  float mrow = -3e38f;           // running max (log2 domain) for q-row q32

  const f16x8 onesf = {1, 1, 1, 1, 1, 1, 1, 1};

  auto stage = [&](int kb, int vb, int t) {
    const _Float16* gk1 = gkA + (size_t)t * 64 * DEPTH;
    const _Float16* gk2 = gkB + (size_t)t * 64 * DEPTH;
    const _Float16* gv1 = gvA + t * 64;
    const _Float16* gv2 = gvB + t * 64;
    GLOAD_LDS(gk1, &Kl[kb][(16 * w) * 64]);
    GLOAD_LDS(gk2, &Kl[kb][(16 * w + 8) * 64]);
    GLOAD_LDS(gv1, &Vl[vb][(16 * w) * 64]);
    GLOAD_LDS(gv2, &Vl[vb][(16 * w + 8) * 64]);
  };

  // QK^T swapped: st = mfma(K, Q): C[key][q], q = q32 lane-local
  auto qkt = [&](int kb, f32x16& s0, f32x16& s1) {
    f32x16 z = {};
    s0 = z; s1 = z;
    __builtin_amdgcn_s_setprio(1);
    #pragma unroll
    for (int c = 0; c < 4; ++c) {
      f16x8 kf0 = *(const f16x8*)&Kl[kb][q32 * 64 + off[c]];
      f16x8 kf1 = *(const f16x8*)&Kl[kb][(32 + q32) * 64 + off[c]];
      s0 = mfma32(kf0, qf[c], s0);
      s1 = mfma32(kf1, qf[c], s1);
    }
    __builtin_amdgcn_s_setprio(0);
  };

  auto smax_pv = [&](f32x16& st0, f32x16& st1, int vb) {
    // ---- online softmax: all 32 scores of q-row q32 are in-lane ----
    float mx = fmaxf(st0[0], st1[0]);
    #pragma unroll
    for (int r = 1; r < 16; ++r) mx = fmaxf(mx, fmaxf(st0[r], st1[r]));
    if (!__all(mx - mrow <= 8.0f)) {       // defer-max THR=8
      mx = fmaxf(mx, __shfl_xor(mx, 32));
      float mnew = fmaxf(mrow, mx);
      float sc = EXP2(mrow - mnew);
      mrow = mnew;
      #pragma unroll
      for (int r = 0; r < 16; ++r) {
        const int crow = (r & 3) + 8 * (r >> 2) + 4 * hi;
        float scb = __shfl(sc, crow);
        acc0[r] *= scb;
        acc1[r] *= scb;
        dacc[r] *= scb;
      }
    }
    float p0[16], p1[16];
    #pragma unroll
    for (int r = 0; r < 16; ++r) {
      p0[r] = EXP2(st0[r] - mrow);
      p1[r] = EXP2(st1[r] - mrow);
    }

    // ---- P -> PV A-fragments in-register (cvt_pk + permlane32_swap) ----
    f16x8 pa[4];
    auto mkpa = [&](const float* pp, f16x8* dst) {
      #pragma unroll
      for (int sl = 0; sl < 2; ++sl) {
        unsigned x0 = pkbits(pp[8 * sl + 0], pp[8 * sl + 1]);
        unsigned x1 = pkbits(pp[8 * sl + 2], pp[8 * sl + 3]);
        unsigned y0 = pkbits(pp[8 * sl + 4], pp[8 * sl + 5]);
        unsigned y1 = pkbits(pp[8 * sl + 6], pp[8 * sl + 7]);
        asm("v_permlane32_swap_b32 %0, %1" : "+v"(x0), "+v"(y0));
        asm("v_permlane32_swap_b32 %0, %1" : "+v"(x1), "+v"(y1));
        union { unsigned u[4]; f16x8 v; } pu;
        pu.u[0] = x0; pu.u[1] = x1; pu.u[2] = y0; pu.u[3] = y1;
        dst[sl] = pu.v;
      }
    };
    mkpa(p0, &pa[0]);
    mkpa(p1, &pa[2]);

    // ---- PV + den: acc += pa[s] x V^T rows; dacc += pa[s] x 1 ----
    __builtin_amdgcn_s_setprio(1);
    #pragma unroll
    for (int s = 0; s < 4; ++s) {
      f16x8 vf0 = *(const f16x8*)&Vl[vb][q32 * 64 + off[s]];
      f16x8 vf1 = *(const f16x8*)&Vl[vb][(32 + q32) * 64 + off[s]];
      acc0 = mfma32(pa[s], vf0, acc0);
      acc1 = mfma32(pa[s], vf1, acc1);
      dacc = mfma32(pa[s], onesf, dacc);
    }
    __builtin_amdgcn_s_setprio(0);
  };

  // ---- pipeline: QK^T one tile ahead of softmax/PV; 1 barrier per tile ----
  f32x16 stA0, stA1, stB0, stB1;
  stage(0, 0, 0);
  __syncthreads();               // tile 0 visible
  stage(1, 1, 1);
  qkt(0, stA0, stA1);            // scores(0)
  __syncthreads();               // tile 1 visible
  int va = 0;
  #pragma unroll 1
  for (int t = 0; t < SEQ / 64; t += 2) {
    const int v1 = va == 2 ? 0 : va + 1;
    const int v2 = v1 == 2 ? 0 : v1 + 1;
    if (t + 2 < SEQ / 64) stage(0, v2, t + 2);
    qkt(1, stB0, stB1);          // scores(t+1) — overlaps softmax(t) VALU
    smax_pv(stA0, stA1, va);
    __syncthreads();
    if (t + 3 < SEQ / 64) stage(1, va, t + 3);
    if (t + 2 < SEQ / 64) qkt(0, stA0, stA1);  // scores(t+2)
    smax_pv(stB0, stB1, v1);
    __syncthreads();
    va = v2;
  }

  // ---- epilogue: den in C-layout (cols replicated) -> shfl-free ----
  #pragma unroll
  for (int r = 0; r < 16; ++r) {
    const int crow = (r & 3) + 8 * (r >> 2) + 4 * hi;
    float rden = 1.0f / dacc[r];
    float* po = out + (size_t)(b * SEQ + qb + crow) * DIMS + hoff;
    po[q32] = acc0[r] * rden;
    po[32 + q32] = acc1[r] * rden;
  }
}

extern "C" void kernel_launch(void* const* d_in, const int* in_sizes, int n_in,
                              void* d_out, int out_size, void* d_ws, size_t ws_size,
                              hipStream_t stream) {
  const float* q = (const float*)d_in[0];
  const float* k = (const float*)d_in[1];
  const float* v = (const float*)d_in[2];
  float* out = (float*)d_out;

  // workspace: Khf | Vt, each 2*16*2048*64 fp16 = 8 MiB
  const size_t tsz = (size_t)2 * HEADS * SEQ * DEPTH;  // elements
  _Float16* khf = (_Float16*)d_ws;
  _Float16* vtp = khf + tsz;

  prep_kv<<<4096, 256, 0, stream>>>(k, v, khf, vtp);
  attn_fwd<<<512, 256, 0, stream>>>(q, khf, vtp, out);
}